// Round 14
// baseline (107.317 us; speedup 1.0000x reference)
//
#include <hip/hip_runtime.h>
#include <stdint.h>

#define S_LEN 2048
#define BATCH 2
#define DMODEL 1024
#define NHEAD 16
#define DK 64
#define MROWS (BATCH * S_LEN) /* 4096 */

typedef __attribute__((ext_vector_type(8))) short bf16x8;
typedef __attribute__((ext_vector_type(4))) float f32x4;
typedef __attribute__((ext_vector_type(16))) float f32x16;
typedef __attribute__((ext_vector_type(4))) short short4v;

#define VMCNT(N) asm volatile("s_waitcnt vmcnt(" #N ")" ::: "memory")

__device__ __forceinline__ short f2b(float f) {
    union { float f; uint32_t u; } c; c.f = f;
    uint32_t u = c.u;
    return (short)((u + 0x7fffu + ((u >> 16) & 1u)) >> 16);
}

__device__ __forceinline__ void gload16(const void* g, void* l) {
    __builtin_amdgcn_global_load_lds(
        (const __attribute__((address_space(1))) void*)g,
        (__attribute__((address_space(3))) void*)l, 16, 0, 0);
}

// ---------------------------------------------------------------- fp32 -> bf16
__global__ void cvt_kernel(const float* __restrict__ X, const float* __restrict__ Wq,
                           const float* __restrict__ Wk, const float* __restrict__ Wv,
                           const float* __restrict__ Wo,
                           short* __restrict__ Xb, short* __restrict__ Wqb,
                           short* __restrict__ Wkb, short* __restrict__ Wvb,
                           short* __restrict__ Wob) {
    const float* src; short* dst; int n4;
    switch (blockIdx.y) {
        case 0:  src = X;  dst = Xb;  n4 = MROWS * DMODEL / 4;  break;
        case 1:  src = Wq; dst = Wqb; n4 = DMODEL * DMODEL / 4; break;
        case 2:  src = Wk; dst = Wkb; n4 = DMODEL * DMODEL / 4; break;
        case 3:  src = Wv; dst = Wvb; n4 = DMODEL * DMODEL / 4; break;
        default: src = Wo; dst = Wob; n4 = DMODEL * DMODEL / 4; break;
    }
    for (int i = blockIdx.x * blockDim.x + threadIdx.x; i < n4;
         i += gridDim.x * blockDim.x) {
        float4 v = ((const float4*)src)[i];
        short4v o;
        o[0] = f2b(v.x); o[1] = f2b(v.y); o[2] = f2b(v.z); o[3] = f2b(v.w);
        ((short4v*)dst)[i] = o;
    }
}

// ------------------------------------------------- C = A * Bt^T  (bf16 MFMA)
// 3-deep LDS pipeline, counted vmcnt + raw s_barrier (unchanged from R12).
template <int OUT_F32>
__global__ __launch_bounds__(256) void gemm_bt(
    const short* __restrict__ A,
    const short* __restrict__ Bt0, const short* __restrict__ Bt1,
    const short* __restrict__ Bt2,
    short* __restrict__ Cb0, short* __restrict__ Cb1, short* __restrict__ Cb2,
    float* __restrict__ Cf, int M, int N, int K) {
    __shared__ short sA[3][128 * 32];
    __shared__ short sB[3][128 * 32];

    const short* Bt = Bt0;
    short* Cb = Cb0;
    if (blockIdx.z == 1) { Bt = Bt1; Cb = Cb1; }
    else if (blockIdx.z == 2) { Bt = Bt2; Cb = Cb2; }

    const int tid = threadIdx.x;
    const int lane = tid & 63;
    const int wid = tid >> 6;
    const int wr = wid >> 1, wc = wid & 1;
    const int brow = blockIdx.y * 128;
    const int bcol = blockIdx.x * 128;
    const int lr = lane & 15;
    const int kh = (lane >> 4) << 3;
    const int swg = ((lr >> 1) & 3) << 3;
    const int khs = kh ^ swg;

    f32x4 acc[4][4] = {};

    const int idx0 = tid, idx1 = tid + 256;
    const int ar0 = idx0 >> 2, ak0 = ((idx0 & 3) << 3) ^ (((ar0 >> 1) & 3) << 3);
    const int ar1 = idx1 >> 2, ak1 = ((idx1 & 3) << 3) ^ (((ar1 >> 1) & 3) << 3);

    const short* gA0 = A + (size_t)(brow + ar0) * K + ak0;
    const short* gA1 = A + (size_t)(brow + ar1) * K + ak1;
    const short* gB0 = Bt + (size_t)(bcol + ar0) * K + ak0;
    const short* gB1 = Bt + (size_t)(bcol + ar1) * K + ak1;

#define G_STAGE(KT, PA, PB)                                   \
    do {                                                      \
        const int k0_ = (KT) << 5;                            \
        gload16(gA0 + k0_, (PA) + idx0 * 8);                  \
        gload16(gA1 + k0_, (PA) + idx1 * 8);                  \
        gload16(gB0 + k0_, (PB) + idx0 * 8);                  \
        gload16(gB1 + k0_, (PB) + idx1 * 8);                  \
    } while (0)

    const int nk = K >> 5;
    short* pA0 = &sA[0][0]; short* pA1 = &sA[1][0]; short* pA2 = &sA[2][0];
    short* pB0 = &sB[0][0]; short* pB1 = &sB[1][0]; short* pB2 = &sB[2][0];

    G_STAGE(0, pA0, pB0);
    G_STAGE(1, pA1, pB1);

    for (int kt = 0; kt < nk; ++kt) {
        if (kt == nk - 1) { VMCNT(0); } else { VMCNT(4); }
        __builtin_amdgcn_s_barrier();
        if (kt + 2 < nk) G_STAGE(kt + 2, pA2, pB2);

        bf16x8 a[4], b[4];
#pragma unroll
        for (int mt = 0; mt < 4; ++mt)
            a[mt] = *(const bf16x8*)&pA0[(wr * 64 + mt * 16 + lr) * 32 + khs];
#pragma unroll
        for (int nt = 0; nt < 4; ++nt)
            b[nt] = *(const bf16x8*)&pB0[(wc * 64 + nt * 16 + lr) * 32 + khs];
        __builtin_amdgcn_s_setprio(1);
#pragma unroll
        for (int mt = 0; mt < 4; ++mt)
#pragma unroll
            for (int nt = 0; nt < 4; ++nt)
                acc[mt][nt] = __builtin_amdgcn_mfma_f32_16x16x32_bf16(
                    a[mt], b[nt], acc[mt][nt], 0, 0, 0);
        __builtin_amdgcn_s_setprio(0);

        short* tA = pA0; pA0 = pA1; pA1 = pA2; pA2 = tA;
        short* tB = pB0; pB0 = pB1; pB1 = pB2; pB2 = tB;
    }
#undef G_STAGE

    const int rbase = (lane >> 4) << 2;
    const bool vtrans = (!OUT_F32) && (blockIdx.z == 2);
#pragma unroll
    for (int mt = 0; mt < 4; ++mt) {
#pragma unroll
        for (int nt = 0; nt < 4; ++nt) {
            if (vtrans) {
                int row0 = brow + wr * 64 + mt * 16 + rbase;
                int col = bcol + wc * 64 + nt * 16 + lr;
                int bb = row0 >> 11, key = row0 & 2047;
                int hh = col >> 6, d = col & 63;
                short4v pk;
#pragma unroll
                for (int j = 0; j < 4; ++j) pk[j] = f2b(acc[mt][nt][j]);
                *(short4v*)&Cb[((size_t)((bb * 16 + hh) * 64 + d)) * S_LEN + key] = pk;
            } else {
#pragma unroll
                for (int j = 0; j < 4; ++j) {
                    int row = brow + wr * 64 + mt * 16 + rbase + j;
                    int col = bcol + wc * 64 + nt * 16 + lr;
                    if (OUT_F32)
                        Cf[(size_t)row * N + col] = acc[mt][nt][j];
                    else
                        Cb[(size_t)row * N + col] = f2b(acc[mt][nt][j]);
                }
            }
        }
    }
}

// ------------------------------------------------------------- flash attention
// 32x32x16 MFMA version, P fully in-register (cvt_pk + permlane32_swap).
// v_permlane32_swap_b32 A,B: A' = concat(A_lo,B_lo); B' = concat(A_hi,B_hi)
// (swaps A.row1 with B.row0). Pairing (low-key reg FIRST): (0,2)(1,3)(4,6)(5,7).
// C/D layout: col=lane&31, row=(reg&3)+8*(reg>>2)+4*(lane>>5)  [m74/m101].
__global__ __launch_bounds__(256, 3) void attn_kernel(
    const short* __restrict__ Q, const short* __restrict__ K,
    const short* __restrict__ Vt, short* __restrict__ O,
    const int* __restrict__ vlens) {
    __shared__ short sK[3][64 * 64];
    __shared__ short sV[3][64 * 64];

    const int tid = threadIdx.x;
    const int lane = tid & 63;
    const int w = tid >> 6;
    const int id = blockIdx.x;
    const int xcd = id & 7;
    const int r = id >> 3;
    const int b = (r >> 5) & 1;
    const int h = (xcd << 1) | (r & 1);
    const int qb = (r >> 1) & 15;          // 16 q-tiles of 128 rows
    const int rl_ = lane & 31;             // row-in-32 (q / key / d)
    const int g = lane >> 5;
    const int sw = (lane & 7) << 3;

    int vl = vlens[b];
    if (vl < 0) vl = 0;
    if (vl > S_LEN) vl = S_LEN;
    const bool allm = (vl == 0);
    if (allm) vl = S_LEN;  // qf=0 -> scores 0 -> uniform softmax == reference
    const int nT = (vl + 63) >> 6;
    const int nFull = ((vl & 63) == 0) ? nT : nT - 1;

    const size_t rowbase = (size_t)(b * S_LEN) * DMODEL + h * DK;
    const short* vt = Vt + ((size_t)((b * 16 + h) * 64)) * S_LEN;

    const int q = qb * 128 + w * 32 + rl_;
    const short* qA = Q + rowbase + (size_t)q * DMODEL;
    bf16x8 qf[4];
#pragma unroll
    for (int f = 0; f < 4; ++f)
        qf[f] = *(const bf16x8*)(qA + f * 16 + g * 8);
    if (allm) {
#pragma unroll
        for (int f = 0; f < 4; ++f)
#pragma unroll
            for (int i = 0; i < 8; ++i) qf[f][i] = 0;
    }

    f32x16 oac0 = {}, oac1 = {};
    float m_run = -1e30f, mc = -1e30f, l_run = 0.f;
    const float CEXP = 0.18033688011112042f;   // 0.125 * log2(e)
    const float THRADD = 44.361419556f;        // 8 / CEXP

    int lofs[4];
#pragma unroll
    for (int f = 0; f < 4; ++f)
        lofs[f] = rl_ * 64 + (((f * 16) + g * 8) ^ sw);

    const int kr = tid >> 3;                       // 0..31
    const int kc = (((tid & 7) ^ (kr & 7)) << 3);  // pre-swizzled col
    const short* kBase = K + rowbase + (size_t)kr * DMODEL + kc;
    const short* vBase = vt + (size_t)kr * S_LEN + kc;

#define A_STAGE(T, PK, PV)                                                      \
    do {                                                                        \
        const short* kg_ = kBase + (size_t)((T) * 64) * DMODEL;                 \
        gload16(kg_, (PK) + tid * 8);                                           \
        gload16(kg_ + (size_t)32 * DMODEL, (PK) + (tid + 256) * 8);             \
        const short* vg_ = vBase + (T) * 64;                                    \
        gload16(vg_, (PV) + tid * 8);                                           \
        gload16(vg_ + (size_t)32 * S_LEN, (PV) + (tid + 256) * 8);              \
    } while (0)

#define MK_FRAG(A0, A1, A2, A3)                                                 \
    ({ union { uint32_t u[4]; bf16x8 v; } _f;                                   \
       _f.u[0] = (A0); _f.u[1] = (A1); _f.u[2] = (A2); _f.u[3] = (A3); _f.v; })

#define TILE_BODY(MASKED_C, PK, PV)                                             \
    do {                                                                        \
        constexpr bool MASKED = MASKED_C;                                       \
        f32x16 s0 = {}, s1 = {};                                                \
        __builtin_amdgcn_s_setprio(1);                                          \
        _Pragma("unroll")                                                       \
        for (int f = 0; f < 4; ++f) {                                           \
            bf16x8 ka = *(const bf16x8*)&(PK)[lofs[f]];                         \
            bf16x8 kb2 = *(const bf16x8*)&(PK)[lofs[f] + 2048];                 \
            s0 = __builtin_amdgcn_mfma_f32_32x32x16_bf16(ka, qf[f], s0, 0, 0, 0); \
            s1 = __builtin_amdgcn_mfma_f32_32x32x16_bf16(kb2, qf[f], s1, 0, 0, 0); \
        }                                                                       \
        __builtin_amdgcn_s_setprio(0);                                          \
        if (MASKED) {                                                           \
            _Pragma("unroll")                                                   \
            for (int rg = 0; rg < 16; ++rg) {                                   \
                int key0 = t * 64 + (rg & 3) + 8 * (rg >> 2) + 4 * g;           \
                if (key0 >= vl) s0[rg] = -3.0e38f;                              \
                if (key0 + 32 >= vl) s1[rg] = -3.0e38f;                         \
            }                                                                   \
        }                                                                       \
        float x0 = fmaxf(fmaxf(s0[0], s0[1]), fmaxf(s0[2], s0[3]));             \
        float x1 = fmaxf(fmaxf(s0[4], s0[5]), fmaxf(s0[6], s0[7]));             \
        float x2 = fmaxf(fmaxf(s0[8], s0[9]), fmaxf(s0[10], s0[11]));           \
        float x3 = fmaxf(fmaxf(s0[12], s0[13]), fmaxf(s0[14], s0[15]));         \
        float x4 = fmaxf(fmaxf(s1[0], s1[1]), fmaxf(s1[2], s1[3]));             \
        float x5 = fmaxf(fmaxf(s1[4], s1[5]), fmaxf(s1[6], s1[7]));             \
        float x6 = fmaxf(fmaxf(s1[8], s1[9]), fmaxf(s1[10], s1[11]));           \
        float x7 = fmaxf(fmaxf(s1[12], s1[13]), fmaxf(s1[14], s1[15]));         \
        float px = fmaxf(fmaxf(fmaxf(x0, x1), fmaxf(x2, x3)),                   \
                         fmaxf(fmaxf(x4, x5), fmaxf(x6, x7)));                  \
        if (__any(px > m_run + THRADD)) {                                       \
            float mx = fmaxf(px, __shfl_xor(px, 32));                           \
            mx = fmaxf(mx, m_run);                                              \
            float scl = __builtin_exp2f((m_run - mx) * CEXP);                   \
            m_run = mx; mc = mx * CEXP;                                         \
            l_run *= scl;                                                       \
            _Pragma("unroll")                                                   \
            for (int i = 0; i < 16; ++i) { oac0[i] *= scl; oac1[i] *= scl; }    \
        }                                                                       \
        uint32_t P0[8], P1[8];                                                  \
        float ls = 0.f;                                                         \
        _Pragma("unroll")                                                       \
        for (int i = 0; i < 8; ++i) {                                           \
            float a0 = __builtin_exp2f(__builtin_fmaf(s0[2 * i], CEXP, -mc));   \
            float a1 = __builtin_exp2f(__builtin_fmaf(s0[2 * i + 1], CEXP, -mc)); \
            float b0 = __builtin_exp2f(__builtin_fmaf(s1[2 * i], CEXP, -mc));   \
            float b1 = __builtin_exp2f(__builtin_fmaf(s1[2 * i + 1], CEXP, -mc)); \
            ls += (a0 + a1) + (b0 + b1);                                        \
            asm("v_cvt_pk_bf16_f32 %0, %1, %2" : "=v"(P0[i]) : "v"(a0), "v"(a1)); \
            asm("v_cvt_pk_bf16_f32 %0, %1, %2" : "=v"(P1[i]) : "v"(b0), "v"(b1)); \
        }                                                                       \
        l_run += ls;                                                            \
        asm volatile("v_permlane32_swap_b32 %0, %1" : "+v"(P0[0]), "+v"(P0[2])); \
        asm volatile("v_permlane32_swap_b32 %0, %1" : "+v"(P0[1]), "+v"(P0[3])); \
        asm volatile("v_permlane32_swap_b32 %0, %1" : "+v"(P0[4]), "+v"(P0[6])); \
        asm volatile("v_permlane32_swap_b32 %0, %1" : "+v"(P0[5]), "+v"(P0[7])); \
        asm volatile("v_permlane32_swap_b32 %0, %1" : "+v"(P1[0]), "+v"(P1[2])); \
        asm volatile("v_permlane32_swap_b32 %0, %1" : "+v"(P1[1]), "+v"(P1[3])); \
        asm volatile("v_permlane32_swap_b32 %0, %1" : "+v"(P1[4]), "+v"(P1[6])); \
        asm volatile("v_permlane32_swap_b32 %0, %1" : "+v"(P1[5]), "+v"(P1[7])); \
        bf16x8 F0 = MK_FRAG(P0[0], P0[1], P0[2], P0[3]);                        \
        bf16x8 F1 = MK_FRAG(P0[4], P0[5], P0[6], P0[7]);                        \
        bf16x8 F2 = MK_FRAG(P1[0], P1[1], P1[2], P1[3]);                        \
        bf16x8 F3 = MK_FRAG(P1[4], P1[5], P1[6], P1[7]);                        \
        __builtin_amdgcn_s_setprio(1);                                          \
        {                                                                       \
            bf16x8 v0 = *(const bf16x8*)&(PV)[lofs[0]];                         \
            bf16x8 v1 = *(const bf16x8*)&(PV)[lofs[0] + 2048];                  \
            oac0 = __builtin_amdgcn_mfma_f32_32x32x16_bf16(v0, F0, oac0, 0, 0, 0); \
            oac1 = __builtin_amdgcn_mfma_f32_32x32x16_bf16(v1, F0, oac1, 0, 0, 0); \
            v0 = *(const bf16x8*)&(PV)[lofs[1]];                                \
            v1 = *(const bf16x8*)&(PV)[lofs[1] + 2048];                         \
            oac0 = __builtin_amdgcn_mfma_f32_32x32x16_bf16(v0, F1, oac0, 0, 0, 0); \
            oac1 = __builtin_amdgcn_mfma_f32_32x32x16_bf16(v1, F1, oac1, 0, 0, 0); \
            v0 = *(const bf16x8*)&(PV)[lofs[2]];                                \
            v1 = *(const bf16x8*)&(PV)[lofs[2] + 2048];                         \
            oac0 = __builtin_amdgcn_mfma_f32_32x32x16_bf16(v0, F2, oac0, 0, 0, 0); \
            oac1 = __builtin_amdgcn_mfma_f32_32x32x16_bf16(v1, F2, oac1, 0, 0, 0); \
            v0 = *(const bf16x8*)&(PV)[lofs[3]];                                \
            v1 = *(const bf16x8*)&(PV)[lofs[3] + 2048];                         \
            oac0 = __builtin_amdgcn_mfma_f32_32x32x16_bf16(v0, F3, oac0, 0, 0, 0); \
            oac1 = __builtin_amdgcn_mfma_f32_32x32x16_bf16(v1, F3, oac1, 0, 0, 0); \
        }                                                                       \
        __builtin_amdgcn_s_setprio(0);                                          \
    } while (0)

    short* pK0 = &sK[0][0]; short* pK1 = &sK[1][0]; short* pK2 = &sK[2][0];
    short* pV0 = &sV[0][0]; short* pV1 = &sV[1][0]; short* pV2 = &sV[2][0];

    A_STAGE(0, pK0, pV0);
    if (nT > 1) A_STAGE(1, pK1, pV1);

    for (int t = 0; t < nT; ++t) {
        if (t == nT - 1) { VMCNT(0); } else { VMCNT(4); }
        __builtin_amdgcn_s_barrier();
        if (t + 2 < nT) A_STAGE(t + 2, pK2, pV2);

        if (t < nFull) TILE_BODY(false, pK0, pV0);
        else TILE_BODY(true, pK0, pV0);

        short* tK = pK0; pK0 = pK1; pK1 = pK2; pK2 = tK;
        short* tV = pV0; pV0 = pV1; pV1 = pV2; pV2 = tV;
    }
#undef TILE_BODY
#undef A_STAGE
#undef MK_FRAG

    // denominator: own-q partial + partner half
    float lt = l_run + __shfl_xor(l_run, 32);
    float rl2 = 1.f / lt;

    short* orow = O + rowbase + (size_t)q * DMODEL;
#pragma unroll
    for (int r2 = 0; r2 < 4; ++r2) {
        short4v pk0, pk1;
#pragma unroll
        for (int j = 0; j < 4; ++j) {
            pk0[j] = f2b(oac0[r2 * 4 + j] * rl2);
            pk1[j] = f2b(oac1[r2 * 4 + j] * rl2);
        }
        int d0 = r2 * 8 + 4 * g;
        *(short4v*)&orow[d0] = pk0;
        *(short4v*)&orow[32 + d0] = pk1;
    }
}

extern "C" void kernel_launch(void* const* d_in, const int* in_sizes, int n_in,
                              void* d_out, int out_size, void* d_ws, size_t ws_size,
                              hipStream_t stream) {
    const float* X = (const float*)d_in[0];
    const int* vlens = (const int*)d_in[1];
    const float* Wq = (const float*)d_in[2];
    const float* Wk = (const float*)d_in[3];
    const float* Wv = (const float*)d_in[4];
    const float* Wo = (const float*)d_in[5];
    float* out = (float*)d_out;

    short* Xb = (short*)d_ws;
    short* Wqb = Xb + (size_t)MROWS * DMODEL;
    short* Wkb = Wqb + (size_t)DMODEL * DMODEL;
    short* Wvb = Wkb + (size_t)DMODEL * DMODEL;
    short* Wob = Wvb + (size_t)DMODEL * DMODEL;
    short* Qb = Wob + (size_t)DMODEL * DMODEL;
    short* Kb = Qb + (size_t)MROWS * DMODEL;
    short* Vtb = Kb + (size_t)MROWS * DMODEL;  // Vt[b][h][d][key]
    short* Ob = Vtb + (size_t)MROWS * DMODEL;

    cvt_kernel<<<dim3(512, 5), 256, 0, stream>>>(X, Wq, Wk, Wv, Wo, Xb, Wqb, Wkb,
                                                 Wvb, Wob);
    gemm_bt<0><<<dim3(8, 32, 3), 256, 0, stream>>>(Xb, Wqb, Wkb, Wvb, Qb, Kb, Vtb,
                                                   nullptr, MROWS, DMODEL, DMODEL);
    attn_kernel<<<dim3(512), 256, 0, stream>>>(Qb, Kb, Vtb, Ob, vlens);
    gemm_bt<1><<<dim3(8, 32, 1), 256, 0, stream>>>(Ob, Wob, Wob, Wob, nullptr,
                                                   nullptr, nullptr, out, MROWS,
                                                   DMODEL, DMODEL);
}

// Round 16
// 105.405 us; speedup vs baseline: 1.0181x; 1.0181x over previous
//
#include <hip/hip_runtime.h>
#include <stdint.h>

#define S_LEN 2048
#define BATCH 2
#define DMODEL 1024
#define NHEAD 16
#define DK 64
#define MROWS (BATCH * S_LEN) /* 4096 */

typedef __attribute__((ext_vector_type(8))) short bf16x8;
typedef __attribute__((ext_vector_type(4))) float f32x4;
typedef __attribute__((ext_vector_type(16))) float f32x16;
typedef __attribute__((ext_vector_type(4))) short short4v;

#define VMCNT(N) asm volatile("s_waitcnt vmcnt(" #N ")" ::: "memory")

__device__ __forceinline__ short f2b(float f) {
    union { float f; uint32_t u; } c; c.f = f;
    uint32_t u = c.u;
    return (short)((u + 0x7fffu + ((u >> 16) & 1u)) >> 16);
}

__device__ __forceinline__ void gload16(const void* g, void* l) {
    __builtin_amdgcn_global_load_lds(
        (const __attribute__((address_space(1))) void*)g,
        (__attribute__((address_space(3))) void*)l, 16, 0, 0);
}

// ---------------------------------------------------------------- fp32 -> bf16
__global__ void cvt_kernel(const float* __restrict__ X, const float* __restrict__ Wq,
                           const float* __restrict__ Wk, const float* __restrict__ Wv,
                           const float* __restrict__ Wo,
                           short* __restrict__ Xb, short* __restrict__ Wqb,
                           short* __restrict__ Wkb, short* __restrict__ Wvb,
                           short* __restrict__ Wob) {
    const float* src; short* dst; int n4;
    switch (blockIdx.y) {
        case 0:  src = X;  dst = Xb;  n4 = MROWS * DMODEL / 4;  break;
        case 1:  src = Wq; dst = Wqb; n4 = DMODEL * DMODEL / 4; break;
        case 2:  src = Wk; dst = Wkb; n4 = DMODEL * DMODEL / 4; break;
        case 3:  src = Wv; dst = Wvb; n4 = DMODEL * DMODEL / 4; break;
        default: src = Wo; dst = Wob; n4 = DMODEL * DMODEL / 4; break;
    }
    for (int i = blockIdx.x * blockDim.x + threadIdx.x; i < n4;
         i += gridDim.x * blockDim.x) {
        float4 v = ((const float4*)src)[i];
        short4v o;
        o[0] = f2b(v.x); o[1] = f2b(v.y); o[2] = f2b(v.z); o[3] = f2b(v.w);
        ((short4v*)dst)[i] = o;
    }
}

// ------------------------------------------------- C = A * Bt^T  (bf16 MFMA)
// 3-deep LDS pipeline, counted vmcnt + raw s_barrier (unchanged from R12).
template <int OUT_F32>
__global__ __launch_bounds__(256) void gemm_bt(
    const short* __restrict__ A,
    const short* __restrict__ Bt0, const short* __restrict__ Bt1,
    const short* __restrict__ Bt2,
    short* __restrict__ Cb0, short* __restrict__ Cb1, short* __restrict__ Cb2,
    float* __restrict__ Cf, int M, int N, int K) {
    __shared__ short sA[3][128 * 32];
    __shared__ short sB[3][128 * 32];

    const short* Bt = Bt0;
    short* Cb = Cb0;
    if (blockIdx.z == 1) { Bt = Bt1; Cb = Cb1; }
    else if (blockIdx.z == 2) { Bt = Bt2; Cb = Cb2; }

    const int tid = threadIdx.x;
    const int lane = tid & 63;
    const int wid = tid >> 6;
    const int wr = wid >> 1, wc = wid & 1;
    const int brow = blockIdx.y * 128;
    const int bcol = blockIdx.x * 128;
    const int lr = lane & 15;
    const int kh = (lane >> 4) << 3;
    const int swg = ((lr >> 1) & 3) << 3;
    const int khs = kh ^ swg;

    f32x4 acc[4][4] = {};

    const int idx0 = tid, idx1 = tid + 256;
    const int ar0 = idx0 >> 2, ak0 = ((idx0 & 3) << 3) ^ (((ar0 >> 1) & 3) << 3);
    const int ar1 = idx1 >> 2, ak1 = ((idx1 & 3) << 3) ^ (((ar1 >> 1) & 3) << 3);

    const short* gA0 = A + (size_t)(brow + ar0) * K + ak0;
    const short* gA1 = A + (size_t)(brow + ar1) * K + ak1;
    const short* gB0 = Bt + (size_t)(bcol + ar0) * K + ak0;
    const short* gB1 = Bt + (size_t)(bcol + ar1) * K + ak1;

#define G_STAGE(KT, PA, PB)                                   \
    do {                                                      \
        const int k0_ = (KT) << 5;                            \
        gload16(gA0 + k0_, (PA) + idx0 * 8);                  \
        gload16(gA1 + k0_, (PA) + idx1 * 8);                  \
        gload16(gB0 + k0_, (PB) + idx0 * 8);                  \
        gload16(gB1 + k0_, (PB) + idx1 * 8);                  \
    } while (0)

    const int nk = K >> 5;
    short* pA0 = &sA[0][0]; short* pA1 = &sA[1][0]; short* pA2 = &sA[2][0];
    short* pB0 = &sB[0][0]; short* pB1 = &sB[1][0]; short* pB2 = &sB[2][0];

    G_STAGE(0, pA0, pB0);
    G_STAGE(1, pA1, pB1);

    for (int kt = 0; kt < nk; ++kt) {
        if (kt == nk - 1) { VMCNT(0); } else { VMCNT(4); }
        __builtin_amdgcn_s_barrier();
        if (kt + 2 < nk) G_STAGE(kt + 2, pA2, pB2);

        bf16x8 a[4], b[4];
#pragma unroll
        for (int mt = 0; mt < 4; ++mt)
            a[mt] = *(const bf16x8*)&pA0[(wr * 64 + mt * 16 + lr) * 32 + khs];
#pragma unroll
        for (int nt = 0; nt < 4; ++nt)
            b[nt] = *(const bf16x8*)&pB0[(wc * 64 + nt * 16 + lr) * 32 + khs];
        __builtin_amdgcn_s_setprio(1);
#pragma unroll
        for (int mt = 0; mt < 4; ++mt)
#pragma unroll
            for (int nt = 0; nt < 4; ++nt)
                acc[mt][nt] = __builtin_amdgcn_mfma_f32_16x16x32_bf16(
                    a[mt], b[nt], acc[mt][nt], 0, 0, 0);
        __builtin_amdgcn_s_setprio(0);

        short* tA = pA0; pA0 = pA1; pA1 = pA2; pA2 = tA;
        short* tB = pB0; pB0 = pB1; pB1 = pB2; pB2 = tB;
    }
#undef G_STAGE

    const int rbase = (lane >> 4) << 2;
    const bool vtrans = (!OUT_F32) && (blockIdx.z == 2);
#pragma unroll
    for (int mt = 0; mt < 4; ++mt) {
#pragma unroll
        for (int nt = 0; nt < 4; ++nt) {
            if (vtrans) {
                int row0 = brow + wr * 64 + mt * 16 + rbase;
                int col = bcol + wc * 64 + nt * 16 + lr;
                int bb = row0 >> 11, key = row0 & 2047;
                int hh = col >> 6, d = col & 63;
                short4v pk;
#pragma unroll
                for (int j = 0; j < 4; ++j) pk[j] = f2b(acc[mt][nt][j]);
                *(short4v*)&Cb[((size_t)((bb * 16 + hh) * 64 + d)) * S_LEN + key] = pk;
            } else {
#pragma unroll
                for (int j = 0; j < 4; ++j) {
                    int row = brow + wr * 64 + mt * 16 + rbase + j;
                    int col = bcol + wc * 64 + nt * 16 + lr;
                    if (OUT_F32)
                        Cf[(size_t)row * N + col] = acc[mt][nt][j];
                    else
                        Cb[(size_t)row * N + col] = f2b(acc[mt][nt][j]);
                }
            }
        }
    }
}

// ------------------------------------------------------------- flash attention
// 32x32x16 MFMA, P in-register (cvt_pk + permlane32_swap, R14-verified).
// Conflict-free LDS swizzle: granule = 8r + (c ^ (r&7) ^ ((r>>3)&3)).
// 4-deep K/V pipeline: stage t+3 ahead, steady-state VMCNT(8), drain 8->4->0.
// Buffers addressed by OFFSET off one base (no LDS pointer arrays - compiler
// cannot static-init addrspacecast arrays).
__global__ __launch_bounds__(256, 2) void attn_kernel(
    const short* __restrict__ Q, const short* __restrict__ K,
    const short* __restrict__ Vt, short* __restrict__ O,
    const int* __restrict__ vlens) {
    __shared__ short sK[4][64 * 64];
    __shared__ short sV[4][64 * 64];

    const int tid = threadIdx.x;
    const int lane = tid & 63;
    const int w = tid >> 6;
    const int id = blockIdx.x;
    const int xcd = id & 7;
    const int r = id >> 3;
    const int b = (r >> 5) & 1;
    const int h = (xcd << 1) | (r & 1);
    const int qb = (r >> 1) & 15;          // 16 q-tiles of 128 rows
    const int rl_ = lane & 31;             // row-in-32 (q / key / d)
    const int g = lane >> 5;

    int vl = vlens[b];
    if (vl < 0) vl = 0;
    if (vl > S_LEN) vl = S_LEN;
    const bool allm = (vl == 0);
    if (allm) vl = S_LEN;  // qf=0 -> scores 0 -> uniform softmax == reference
    const int nT = (vl + 63) >> 6;
    const int nFull = ((vl & 63) == 0) ? nT : nT - 1;

    const size_t rowbase = (size_t)(b * S_LEN) * DMODEL + h * DK;
    const short* vt = Vt + ((size_t)((b * 16 + h) * 64)) * S_LEN;

    const int q = qb * 128 + w * 32 + rl_;
    const short* qA = Q + rowbase + (size_t)q * DMODEL;
    bf16x8 qf[4];
#pragma unroll
    for (int f = 0; f < 4; ++f)
        qf[f] = *(const bf16x8*)(qA + f * 16 + g * 8);
    if (allm) {
#pragma unroll
        for (int f = 0; f < 4; ++f)
#pragma unroll
            for (int i = 0; i < 8; ++i) qf[f][i] = 0;
    }

    f32x16 oac0 = {}, oac1 = {};
    float m_run = -1e30f, mc = -1e30f, l_run = 0.f;
    const float CEXP = 0.18033688011112042f;   // 0.125 * log2(e)
    const float THRADD = 44.361419556f;        // 8 / CEXP

    // read-side: slot = c ^ (r&7) ^ ((r>>3)&3), r = rl_
    const int rsw = (((rl_ & 7) ^ ((rl_ >> 3) & 3)) << 3);
    int lofs[4];
#pragma unroll
    for (int f = 0; f < 4; ++f)
        lofs[f] = rl_ * 64 + ((f * 16 + g * 8) ^ rsw);

    // staging: row kr = tid>>3 (chunk1: kr+32, swizzle invariant under +32);
    // source col pre-swizzled to match.
    const int kr = tid >> 3;                       // 0..31
    const int kc = (((tid & 7) ^ (kr & 7) ^ ((kr >> 3) & 3)) << 3);
    const short* kBase = K + rowbase + (size_t)kr * DMODEL + kc;
    const short* vBase = vt + (size_t)kr * S_LEN + kc;

    short* const sK0 = &sK[0][0];
    short* const sV0 = &sV[0][0];
#define KBUF(i) (sK0 + (i) * 4096)
#define VBUF(i) (sV0 + (i) * 4096)

#define A_STAGE(T, PK, PV)                                                      \
    do {                                                                        \
        const short* kg_ = kBase + (size_t)((T) * 64) * DMODEL;                 \
        gload16(kg_, (PK) + tid * 8);                                           \
        gload16(kg_ + (size_t)32 * DMODEL, (PK) + (tid + 256) * 8);             \
        const short* vg_ = vBase + (T) * 64;                                    \
        gload16(vg_, (PV) + tid * 8);                                           \
        gload16(vg_ + (size_t)32 * S_LEN, (PV) + (tid + 256) * 8);              \
    } while (0)

#define MK_FRAG(A0, A1, A2, A3)                                                 \
    ({ union { uint32_t u[4]; bf16x8 v; } _f;                                   \
       _f.u[0] = (A0); _f.u[1] = (A1); _f.u[2] = (A2); _f.u[3] = (A3); _f.v; })

#define TILE_BODY(MASKED_C, PK, PV)                                             \
    do {                                                                        \
        constexpr bool MASKED = MASKED_C;                                       \
        f32x16 s0 = {}, s1 = {};                                                \
        __builtin_amdgcn_s_setprio(1);                                          \
        _Pragma("unroll")                                                       \
        for (int f = 0; f < 4; ++f) {                                           \
            bf16x8 ka = *(const bf16x8*)&(PK)[lofs[f]];                         \
            bf16x8 kb2 = *(const bf16x8*)&(PK)[lofs[f] + 2048];                 \
            s0 = __builtin_amdgcn_mfma_f32_32x32x16_bf16(ka, qf[f], s0, 0, 0, 0); \
            s1 = __builtin_amdgcn_mfma_f32_32x32x16_bf16(kb2, qf[f], s1, 0, 0, 0); \
        }                                                                       \
        __builtin_amdgcn_s_setprio(0);                                          \
        if (MASKED) {                                                           \
            _Pragma("unroll")                                                   \
            for (int rg = 0; rg < 16; ++rg) {                                   \
                int key0 = t * 64 + (rg & 3) + 8 * (rg >> 2) + 4 * g;           \
                if (key0 >= vl) s0[rg] = -3.0e38f;                              \
                if (key0 + 32 >= vl) s1[rg] = -3.0e38f;                         \
            }                                                                   \
        }                                                                       \
        float x0 = fmaxf(fmaxf(s0[0], s0[1]), fmaxf(s0[2], s0[3]));             \
        float x1 = fmaxf(fmaxf(s0[4], s0[5]), fmaxf(s0[6], s0[7]));             \
        float x2 = fmaxf(fmaxf(s0[8], s0[9]), fmaxf(s0[10], s0[11]));           \
        float x3 = fmaxf(fmaxf(s0[12], s0[13]), fmaxf(s0[14], s0[15]));         \
        float x4 = fmaxf(fmaxf(s1[0], s1[1]), fmaxf(s1[2], s1[3]));             \
        float x5 = fmaxf(fmaxf(s1[4], s1[5]), fmaxf(s1[6], s1[7]));             \
        float x6 = fmaxf(fmaxf(s1[8], s1[9]), fmaxf(s1[10], s1[11]));           \
        float x7 = fmaxf(fmaxf(s1[12], s1[13]), fmaxf(s1[14], s1[15]));         \
        float px = fmaxf(fmaxf(fmaxf(x0, x1), fmaxf(x2, x3)),                   \
                         fmaxf(fmaxf(x4, x5), fmaxf(x6, x7)));                  \
        if (__any(px > m_run + THRADD)) {                                       \
            float mx = fmaxf(px, __shfl_xor(px, 32));                           \
            mx = fmaxf(mx, m_run);                                              \
            float scl = __builtin_exp2f((m_run - mx) * CEXP);                   \
            m_run = mx; mc = mx * CEXP;                                         \
            l_run *= scl;                                                       \
            _Pragma("unroll")                                                   \
            for (int i = 0; i < 16; ++i) { oac0[i] *= scl; oac1[i] *= scl; }    \
        }                                                                       \
        uint32_t P0[8], P1[8];                                                  \
        float ls = 0.f;                                                         \
        _Pragma("unroll")                                                       \
        for (int i = 0; i < 8; ++i) {                                           \
            float a0 = __builtin_exp2f(__builtin_fmaf(s0[2 * i], CEXP, -mc));   \
            float a1 = __builtin_exp2f(__builtin_fmaf(s0[2 * i + 1], CEXP, -mc)); \
            float b0 = __builtin_exp2f(__builtin_fmaf(s1[2 * i], CEXP, -mc));   \
            float b1 = __builtin_exp2f(__builtin_fmaf(s1[2 * i + 1], CEXP, -mc)); \
            ls += (a0 + a1) + (b0 + b1);                                        \
            asm("v_cvt_pk_bf16_f32 %0, %1, %2" : "=v"(P0[i]) : "v"(a0), "v"(a1)); \
            asm("v_cvt_pk_bf16_f32 %0, %1, %2" : "=v"(P1[i]) : "v"(b0), "v"(b1)); \
        }                                                                       \
        l_run += ls;                                                            \
        asm volatile("v_permlane32_swap_b32 %0, %1" : "+v"(P0[0]), "+v"(P0[2])); \
        asm volatile("v_permlane32_swap_b32 %0, %1" : "+v"(P0[1]), "+v"(P0[3])); \
        asm volatile("v_permlane32_swap_b32 %0, %1" : "+v"(P0[4]), "+v"(P0[6])); \
        asm volatile("v_permlane32_swap_b32 %0, %1" : "+v"(P0[5]), "+v"(P0[7])); \
        asm volatile("v_permlane32_swap_b32 %0, %1" : "+v"(P1[0]), "+v"(P1[2])); \
        asm volatile("v_permlane32_swap_b32 %0, %1" : "+v"(P1[1]), "+v"(P1[3])); \
        asm volatile("v_permlane32_swap_b32 %0, %1" : "+v"(P1[4]), "+v"(P1[6])); \
        asm volatile("v_permlane32_swap_b32 %0, %1" : "+v"(P1[5]), "+v"(P1[7])); \
        bf16x8 F0 = MK_FRAG(P0[0], P0[1], P0[2], P0[3]);                        \
        bf16x8 F1 = MK_FRAG(P0[4], P0[5], P0[6], P0[7]);                        \
        bf16x8 F2 = MK_FRAG(P1[0], P1[1], P1[2], P1[3]);                        \
        bf16x8 F3 = MK_FRAG(P1[4], P1[5], P1[6], P1[7]);                        \
        __builtin_amdgcn_s_setprio(1);                                          \
        {                                                                       \
            bf16x8 v0 = *(const bf16x8*)&(PV)[lofs[0]];                         \
            bf16x8 v1 = *(const bf16x8*)&(PV)[lofs[0] + 2048];                  \
            oac0 = __builtin_amdgcn_mfma_f32_32x32x16_bf16(v0, F0, oac0, 0, 0, 0); \
            oac1 = __builtin_amdgcn_mfma_f32_32x32x16_bf16(v1, F0, oac1, 0, 0, 0); \
            v0 = *(const bf16x8*)&(PV)[lofs[1]];                                \
            v1 = *(const bf16x8*)&(PV)[lofs[1] + 2048];                         \
            oac0 = __builtin_amdgcn_mfma_f32_32x32x16_bf16(v0, F1, oac0, 0, 0, 0); \
            oac1 = __builtin_amdgcn_mfma_f32_32x32x16_bf16(v1, F1, oac1, 0, 0, 0); \
            v0 = *(const bf16x8*)&(PV)[lofs[2]];                                \
            v1 = *(const bf16x8*)&(PV)[lofs[2] + 2048];                         \
            oac0 = __builtin_amdgcn_mfma_f32_32x32x16_bf16(v0, F2, oac0, 0, 0, 0); \
            oac1 = __builtin_amdgcn_mfma_f32_32x32x16_bf16(v1, F2, oac1, 0, 0, 0); \
            v0 = *(const bf16x8*)&(PV)[lofs[3]];                                \
            v1 = *(const bf16x8*)&(PV)[lofs[3] + 2048];                         \
            oac0 = __builtin_amdgcn_mfma_f32_32x32x16_bf16(v0, F3, oac0, 0, 0, 0); \
            oac1 = __builtin_amdgcn_mfma_f32_32x32x16_bf16(v1, F3, oac1, 0, 0, 0); \
        }                                                                       \
        __builtin_amdgcn_s_setprio(0);                                          \
    } while (0)

    A_STAGE(0, KBUF(0), VBUF(0));
    if (nT > 1) A_STAGE(1, KBUF(1), VBUF(1));
    if (nT > 2) A_STAGE(2, KBUF(2), VBUF(2));

    for (int t = 0; t < nT; ++t) {
        const int rem = nT - 1 - t;          // tiles staged beyond t
        if (rem >= 2) { VMCNT(8); }
        else if (rem == 1) { VMCNT(4); }
        else { VMCNT(0); }
        __builtin_amdgcn_s_barrier();
        if (t + 3 < nT) A_STAGE(t + 3, KBUF((t + 3) & 3), VBUF((t + 3) & 3));

        short* curK = KBUF(t & 3);
        short* curV = VBUF(t & 3);
        if (t < nFull) TILE_BODY(false, curK, curV);
        else TILE_BODY(true, curK, curV);
    }
#undef TILE_BODY
#undef A_STAGE
#undef MK_FRAG
#undef KBUF
#undef VBUF

    // denominator: own-q partial + partner half
    float lt = l_run + __shfl_xor(l_run, 32);
    float rl2 = 1.f / lt;

    short* orow = O + rowbase + (size_t)q * DMODEL;
#pragma unroll
    for (int r2 = 0; r2 < 4; ++r2) {
        short4v pk0, pk1;
#pragma unroll
        for (int j = 0; j < 4; ++j) {
            pk0[j] = f2b(oac0[r2 * 4 + j] * rl2);
            pk1[j] = f2b(oac1[r2 * 4 + j] * rl2);
        }
        int d0 = r2 * 8 + 4 * g;
        *(short4v*)&orow[d0] = pk0;
        *(short4v*)&orow[32 + d0] = pk1;
    }
}

extern "C" void kernel_launch(void* const* d_in, const int* in_sizes, int n_in,
                              void* d_out, int out_size, void* d_ws, size_t ws_size,
                              hipStream_t stream) {
    const float* X = (const float*)d_in[0];
    const int* vlens = (const int*)d_in[1];
    const float* Wq = (const float*)d_in[2];
    const float* Wk = (const float*)d_in[3];
    const float* Wv = (const float*)d_in[4];
    const float* Wo = (const float*)d_in[5];
    float* out = (float*)d_out;

    short* Xb = (short*)d_ws;
    short* Wqb = Xb + (size_t)MROWS * DMODEL;
    short* Wkb = Wqb + (size_t)DMODEL * DMODEL;
    short* Wvb = Wkb + (size_t)DMODEL * DMODEL;
    short* Wob = Wvb + (size_t)DMODEL * DMODEL;
    short* Qb = Wob + (size_t)DMODEL * DMODEL;
    short* Kb = Qb + (size_t)MROWS * DMODEL;
    short* Vtb = Kb + (size_t)MROWS * DMODEL;  // Vt[b][h][d][key]
    short* Ob = Vtb + (size_t)MROWS * DMODEL;

    cvt_kernel<<<dim3(512, 5), 256, 0, stream>>>(X, Wq, Wk, Wv, Wo, Xb, Wqb, Wkb,
                                                 Wvb, Wob);
    gemm_bt<0><<<dim3(8, 32, 3), 256, 0, stream>>>(Xb, Wqb, Wkb, Wvb, Qb, Kb, Vtb,
                                                   nullptr, MROWS, DMODEL, DMODEL);
    attn_kernel<<<dim3(512), 256, 0, stream>>>(Qb, Kb, Vtb, Ob, vlens);
    gemm_bt<1><<<dim3(8, 32, 1), 256, 0, stream>>>(Ob, Wob, Wob, Wob, nullptr,
                                                   nullptr, nullptr, out, MROWS,
                                                   DMODEL, DMODEL);
}

// Round 17
// 102.211 us; speedup vs baseline: 1.0500x; 1.0312x over previous
//
#include <hip/hip_runtime.h>
#include <stdint.h>

#define S_LEN 2048
#define BATCH 2
#define DMODEL 1024
#define NHEAD 16
#define DK 64
#define MROWS (BATCH * S_LEN) /* 4096 */

typedef __attribute__((ext_vector_type(8))) short bf16x8;
typedef __attribute__((ext_vector_type(4))) float f32x4;
typedef __attribute__((ext_vector_type(16))) float f32x16;
typedef __attribute__((ext_vector_type(4))) short short4v;

#define VMCNT(N) asm volatile("s_waitcnt vmcnt(" #N ")" ::: "memory")

__device__ __forceinline__ short f2b(float f) {
    union { float f; uint32_t u; } c; c.f = f;
    uint32_t u = c.u;
    return (short)((u + 0x7fffu + ((u >> 16) & 1u)) >> 16);
}

__device__ __forceinline__ void gload16(const void* g, void* l) {
    __builtin_amdgcn_global_load_lds(
        (const __attribute__((address_space(1))) void*)g,
        (__attribute__((address_space(3))) void*)l, 16, 0, 0);
}

// ---------------------------------------------------------------- fp32 -> bf16
__global__ void cvt_kernel(const float* __restrict__ X, const float* __restrict__ Wq,
                           const float* __restrict__ Wk, const float* __restrict__ Wv,
                           const float* __restrict__ Wo,
                           short* __restrict__ Xb, short* __restrict__ Wqb,
                           short* __restrict__ Wkb, short* __restrict__ Wvb,
                           short* __restrict__ Wob) {
    const float* src; short* dst; int n4;
    switch (blockIdx.y) {
        case 0:  src = X;  dst = Xb;  n4 = MROWS * DMODEL / 4;  break;
        case 1:  src = Wq; dst = Wqb; n4 = DMODEL * DMODEL / 4; break;
        case 2:  src = Wk; dst = Wkb; n4 = DMODEL * DMODEL / 4; break;
        case 3:  src = Wv; dst = Wvb; n4 = DMODEL * DMODEL / 4; break;
        default: src = Wo; dst = Wob; n4 = DMODEL * DMODEL / 4; break;
    }
    for (int i = blockIdx.x * blockDim.x + threadIdx.x; i < n4;
         i += gridDim.x * blockDim.x) {
        float4 v = ((const float4*)src)[i];
        short4v o;
        o[0] = f2b(v.x); o[1] = f2b(v.y); o[2] = f2b(v.z); o[3] = f2b(v.w);
        ((short4v*)dst)[i] = o;
    }
}

// ------------------------------------------------- C = A * Bt^T  (bf16 MFMA)
// 3-deep LDS pipeline, counted vmcnt + raw s_barrier (R12 structure).
// NEW: mask-skip — for z>=1 (K and V projections), blocks whose entire
// 128-key-row range lies beyond ceil64(vl) are never read by attention and
// exit immediately. vl==0 mirrors attn's allm rule (all V rows needed).
template <int OUT_F32>
__global__ __launch_bounds__(256) void gemm_bt(
    const short* __restrict__ A,
    const short* __restrict__ Bt0, const short* __restrict__ Bt1,
    const short* __restrict__ Bt2,
    short* __restrict__ Cb0, short* __restrict__ Cb1, short* __restrict__ Cb2,
    float* __restrict__ Cf, const int* __restrict__ vlens, int M, int N, int K) {
    __shared__ short sA[3][128 * 32];
    __shared__ short sB[3][128 * 32];

    const short* Bt = Bt0;
    short* Cb = Cb0;
    if (blockIdx.z == 1) { Bt = Bt1; Cb = Cb1; }
    else if (blockIdx.z == 2) { Bt = Bt2; Cb = Cb2; }

    const int brow = blockIdx.y * 128;
    if (!OUT_F32 && blockIdx.z >= 1 && vlens) {
        int vlb = vlens[brow >> 11];
        if (vlb <= 0 || vlb > S_LEN) vlb = S_LEN;   // allm / clamp -> keep all
        else vlb = (vlb + 63) & ~63;                // attn reads nT*64 keys
        if ((brow & (S_LEN - 1)) >= vlb) return;    // whole block unused
    }

    const int tid = threadIdx.x;
    const int lane = tid & 63;
    const int wid = tid >> 6;
    const int wr = wid >> 1, wc = wid & 1;
    const int bcol = blockIdx.x * 128;
    const int lr = lane & 15;
    const int kh = (lane >> 4) << 3;
    const int swg = ((lr >> 1) & 3) << 3;
    const int khs = kh ^ swg;

    f32x4 acc[4][4] = {};

    const int idx0 = tid, idx1 = tid + 256;
    const int ar0 = idx0 >> 2, ak0 = ((idx0 & 3) << 3) ^ (((ar0 >> 1) & 3) << 3);
    const int ar1 = idx1 >> 2, ak1 = ((idx1 & 3) << 3) ^ (((ar1 >> 1) & 3) << 3);

    const short* gA0 = A + (size_t)(brow + ar0) * K + ak0;
    const short* gA1 = A + (size_t)(brow + ar1) * K + ak1;
    const short* gB0 = Bt + (size_t)(bcol + ar0) * K + ak0;
    const short* gB1 = Bt + (size_t)(bcol + ar1) * K + ak1;

#define G_STAGE(KT, PA, PB)                                   \
    do {                                                      \
        const int k0_ = (KT) << 5;                            \
        gload16(gA0 + k0_, (PA) + idx0 * 8);                  \
        gload16(gA1 + k0_, (PA) + idx1 * 8);                  \
        gload16(gB0 + k0_, (PB) + idx0 * 8);                  \
        gload16(gB1 + k0_, (PB) + idx1 * 8);                  \
    } while (0)

    const int nk = K >> 5;
    short* pA0 = &sA[0][0]; short* pA1 = &sA[1][0]; short* pA2 = &sA[2][0];
    short* pB0 = &sB[0][0]; short* pB1 = &sB[1][0]; short* pB2 = &sB[2][0];

    G_STAGE(0, pA0, pB0);
    G_STAGE(1, pA1, pB1);

    for (int kt = 0; kt < nk; ++kt) {
        if (kt == nk - 1) { VMCNT(0); } else { VMCNT(4); }
        __builtin_amdgcn_s_barrier();
        if (kt + 2 < nk) G_STAGE(kt + 2, pA2, pB2);

        bf16x8 a[4], b[4];
#pragma unroll
        for (int mt = 0; mt < 4; ++mt)
            a[mt] = *(const bf16x8*)&pA0[(wr * 64 + mt * 16 + lr) * 32 + khs];
#pragma unroll
        for (int nt = 0; nt < 4; ++nt)
            b[nt] = *(const bf16x8*)&pB0[(wc * 64 + nt * 16 + lr) * 32 + khs];
        __builtin_amdgcn_s_setprio(1);
#pragma unroll
        for (int mt = 0; mt < 4; ++mt)
#pragma unroll
            for (int nt = 0; nt < 4; ++nt)
                acc[mt][nt] = __builtin_amdgcn_mfma_f32_16x16x32_bf16(
                    a[mt], b[nt], acc[mt][nt], 0, 0, 0);
        __builtin_amdgcn_s_setprio(0);

        short* tA = pA0; pA0 = pA1; pA1 = pA2; pA2 = tA;
        short* tB = pB0; pB0 = pB1; pB1 = pB2; pB2 = tB;
    }
#undef G_STAGE

    const int rbase = (lane >> 4) << 2;
    const bool vtrans = (!OUT_F32) && (blockIdx.z == 2);
#pragma unroll
    for (int mt = 0; mt < 4; ++mt) {
#pragma unroll
        for (int nt = 0; nt < 4; ++nt) {
            if (vtrans) {
                int row0 = brow + wr * 64 + mt * 16 + rbase;
                int col = bcol + wc * 64 + nt * 16 + lr;
                int bb = row0 >> 11, key = row0 & 2047;
                int hh = col >> 6, d = col & 63;
                short4v pk;
#pragma unroll
                for (int j = 0; j < 4; ++j) pk[j] = f2b(acc[mt][nt][j]);
                *(short4v*)&Cb[((size_t)((bb * 16 + hh) * 64 + d)) * S_LEN + key] = pk;
            } else {
#pragma unroll
                for (int j = 0; j < 4; ++j) {
                    int row = brow + wr * 64 + mt * 16 + rbase + j;
                    int col = bcol + wc * 64 + nt * 16 + lr;
                    if (OUT_F32)
                        Cf[(size_t)row * N + col] = acc[mt][nt][j];
                    else
                        Cb[(size_t)row * N + col] = f2b(acc[mt][nt][j]);
                }
            }
        }
    }
}

// ------------------------------------------------------------- flash attention
// 32x32x16 MFMA, P in-register (cvt_pk + permlane32_swap, R14-verified).
// Conflict-free LDS swizzle: granule = 8r + (c ^ (r&7) ^ ((r>>3)&3)).
// 4-deep K/V pipeline: stage t+3 ahead, steady-state VMCNT(8), drain 8->4->0.
__global__ __launch_bounds__(256, 2) void attn_kernel(
    const short* __restrict__ Q, const short* __restrict__ K,
    const short* __restrict__ Vt, short* __restrict__ O,
    const int* __restrict__ vlens) {
    __shared__ short sK[4][64 * 64];
    __shared__ short sV[4][64 * 64];

    const int tid = threadIdx.x;
    const int lane = tid & 63;
    const int w = tid >> 6;
    const int id = blockIdx.x;
    const int xcd = id & 7;
    const int r = id >> 3;
    const int b = (r >> 5) & 1;
    const int h = (xcd << 1) | (r & 1);
    const int qb = (r >> 1) & 15;          // 16 q-tiles of 128 rows
    const int rl_ = lane & 31;             // row-in-32 (q / key / d)
    const int g = lane >> 5;

    int vl = vlens[b];
    if (vl < 0) vl = 0;
    if (vl > S_LEN) vl = S_LEN;
    const bool allm = (vl == 0);
    if (allm) vl = S_LEN;  // qf=0 -> scores 0 -> uniform softmax == reference
    const int nT = (vl + 63) >> 6;
    const int nFull = ((vl & 63) == 0) ? nT : nT - 1;

    const size_t rowbase = (size_t)(b * S_LEN) * DMODEL + h * DK;
    const short* vt = Vt + ((size_t)((b * 16 + h) * 64)) * S_LEN;

    const int q = qb * 128 + w * 32 + rl_;
    const short* qA = Q + rowbase + (size_t)q * DMODEL;
    bf16x8 qf[4];
#pragma unroll
    for (int f = 0; f < 4; ++f)
        qf[f] = *(const bf16x8*)(qA + f * 16 + g * 8);
    if (allm) {
#pragma unroll
        for (int f = 0; f < 4; ++f)
#pragma unroll
            for (int i = 0; i < 8; ++i) qf[f][i] = 0;
    }

    f32x16 oac0 = {}, oac1 = {};
    float m_run = -1e30f, mc = -1e30f, l_run = 0.f;
    const float CEXP = 0.18033688011112042f;   // 0.125 * log2(e)
    const float THRADD = 44.361419556f;        // 8 / CEXP

    const int rsw = (((rl_ & 7) ^ ((rl_ >> 3) & 3)) << 3);
    int lofs[4];
#pragma unroll
    for (int f = 0; f < 4; ++f)
        lofs[f] = rl_ * 64 + ((f * 16 + g * 8) ^ rsw);

    const int kr = tid >> 3;                       // 0..31
    const int kc = (((tid & 7) ^ (kr & 7) ^ ((kr >> 3) & 3)) << 3);
    const short* kBase = K + rowbase + (size_t)kr * DMODEL + kc;
    const short* vBase = vt + (size_t)kr * S_LEN + kc;

    short* const sK0 = &sK[0][0];
    short* const sV0 = &sV[0][0];
#define KBUF(i) (sK0 + (i) * 4096)
#define VBUF(i) (sV0 + (i) * 4096)

#define A_STAGE(T, PK, PV)                                                      \
    do {                                                                        \
        const short* kg_ = kBase + (size_t)((T) * 64) * DMODEL;                 \
        gload16(kg_, (PK) + tid * 8);                                           \
        gload16(kg_ + (size_t)32 * DMODEL, (PK) + (tid + 256) * 8);             \
        const short* vg_ = vBase + (T) * 64;                                    \
        gload16(vg_, (PV) + tid * 8);                                           \
        gload16(vg_ + (size_t)32 * S_LEN, (PV) + (tid + 256) * 8);              \
    } while (0)

#define MK_FRAG(A0, A1, A2, A3)                                                 \
    ({ union { uint32_t u[4]; bf16x8 v; } _f;                                   \
       _f.u[0] = (A0); _f.u[1] = (A1); _f.u[2] = (A2); _f.u[3] = (A3); _f.v; })

#define TILE_BODY(MASKED_C, PK, PV)                                             \
    do {                                                                        \
        constexpr bool MASKED = MASKED_C;                                       \
        f32x16 s0 = {}, s1 = {};                                                \
        __builtin_amdgcn_s_setprio(1);                                          \
        _Pragma("unroll")                                                       \
        for (int f = 0; f < 4; ++f) {                                           \
            bf16x8 ka = *(const bf16x8*)&(PK)[lofs[f]];                         \
            bf16x8 kb2 = *(const bf16x8*)&(PK)[lofs[f] + 2048];                 \
            s0 = __builtin_amdgcn_mfma_f32_32x32x16_bf16(ka, qf[f], s0, 0, 0, 0); \
            s1 = __builtin_amdgcn_mfma_f32_32x32x16_bf16(kb2, qf[f], s1, 0, 0, 0); \
        }                                                                       \
        __builtin_amdgcn_s_setprio(0);                                          \
        if (MASKED) {                                                           \
            _Pragma("unroll")                                                   \
            for (int rg = 0; rg < 16; ++rg) {                                   \
                int key0 = t * 64 + (rg & 3) + 8 * (rg >> 2) + 4 * g;           \
                if (key0 >= vl) s0[rg] = -3.0e38f;                              \
                if (key0 + 32 >= vl) s1[rg] = -3.0e38f;                         \
            }                                                                   \
        }                                                                       \
        float x0 = fmaxf(fmaxf(s0[0], s0[1]), fmaxf(s0[2], s0[3]));             \
        float x1 = fmaxf(fmaxf(s0[4], s0[5]), fmaxf(s0[6], s0[7]));             \
        float x2 = fmaxf(fmaxf(s0[8], s0[9]), fmaxf(s0[10], s0[11]));           \
        float x3 = fmaxf(fmaxf(s0[12], s0[13]), fmaxf(s0[14], s0[15]));         \
        float x4 = fmaxf(fmaxf(s1[0], s1[1]), fmaxf(s1[2], s1[3]));             \
        float x5 = fmaxf(fmaxf(s1[4], s1[5]), fmaxf(s1[6], s1[7]));             \
        float x6 = fmaxf(fmaxf(s1[8], s1[9]), fmaxf(s1[10], s1[11]));           \
        float x7 = fmaxf(fmaxf(s1[12], s1[13]), fmaxf(s1[14], s1[15]));         \
        float px = fmaxf(fmaxf(fmaxf(x0, x1), fmaxf(x2, x3)),                   \
                         fmaxf(fmaxf(x4, x5), fmaxf(x6, x7)));                  \
        if (__any(px > m_run + THRADD)) {                                       \
            float mx = fmaxf(px, __shfl_xor(px, 32));                           \
            mx = fmaxf(mx, m_run);                                              \
            float scl = __builtin_exp2f((m_run - mx) * CEXP);                   \
            m_run = mx; mc = mx * CEXP;                                         \
            l_run *= scl;                                                       \
            _Pragma("unroll")                                                   \
            for (int i = 0; i < 16; ++i) { oac0[i] *= scl; oac1[i] *= scl; }    \
        }                                                                       \
        uint32_t P0[8], P1[8];                                                  \
        float ls = 0.f;                                                         \
        _Pragma("unroll")                                                       \
        for (int i = 0; i < 8; ++i) {                                           \
            float a0 = __builtin_exp2f(__builtin_fmaf(s0[2 * i], CEXP, -mc));   \
            float a1 = __builtin_exp2f(__builtin_fmaf(s0[2 * i + 1], CEXP, -mc)); \
            float b0 = __builtin_exp2f(__builtin_fmaf(s1[2 * i], CEXP, -mc));   \
            float b1 = __builtin_exp2f(__builtin_fmaf(s1[2 * i + 1], CEXP, -mc)); \
            ls += (a0 + a1) + (b0 + b1);                                        \
            asm("v_cvt_pk_bf16_f32 %0, %1, %2" : "=v"(P0[i]) : "v"(a0), "v"(a1)); \
            asm("v_cvt_pk_bf16_f32 %0, %1, %2" : "=v"(P1[i]) : "v"(b0), "v"(b1)); \
        }                                                                       \
        l_run += ls;                                                            \
        asm volatile("v_permlane32_swap_b32 %0, %1" : "+v"(P0[0]), "+v"(P0[2])); \
        asm volatile("v_permlane32_swap_b32 %0, %1" : "+v"(P0[1]), "+v"(P0[3])); \
        asm volatile("v_permlane32_swap_b32 %0, %1" : "+v"(P0[4]), "+v"(P0[6])); \
        asm volatile("v_permlane32_swap_b32 %0, %1" : "+v"(P0[5]), "+v"(P0[7])); \
        asm volatile("v_permlane32_swap_b32 %0, %1" : "+v"(P1[0]), "+v"(P1[2])); \
        asm volatile("v_permlane32_swap_b32 %0, %1" : "+v"(P1[1]), "+v"(P1[3])); \
        asm volatile("v_permlane32_swap_b32 %0, %1" : "+v"(P1[4]), "+v"(P1[6])); \
        asm volatile("v_permlane32_swap_b32 %0, %1" : "+v"(P1[5]), "+v"(P1[7])); \
        bf16x8 F0 = MK_FRAG(P0[0], P0[1], P0[2], P0[3]);                        \
        bf16x8 F1 = MK_FRAG(P0[4], P0[5], P0[6], P0[7]);                        \
        bf16x8 F2 = MK_FRAG(P1[0], P1[1], P1[2], P1[3]);                        \
        bf16x8 F3 = MK_FRAG(P1[4], P1[5], P1[6], P1[7]);                        \
        __builtin_amdgcn_s_setprio(1);                                          \
        {                                                                       \
            bf16x8 v0 = *(const bf16x8*)&(PV)[lofs[0]];                         \
            bf16x8 v1 = *(const bf16x8*)&(PV)[lofs[0] + 2048];                  \
            oac0 = __builtin_amdgcn_mfma_f32_32x32x16_bf16(v0, F0, oac0, 0, 0, 0); \
            oac1 = __builtin_amdgcn_mfma_f32_32x32x16_bf16(v1, F0, oac1, 0, 0, 0); \
            v0 = *(const bf16x8*)&(PV)[lofs[1]];                                \
            v1 = *(const bf16x8*)&(PV)[lofs[1] + 2048];                         \
            oac0 = __builtin_amdgcn_mfma_f32_32x32x16_bf16(v0, F1, oac0, 0, 0, 0); \
            oac1 = __builtin_amdgcn_mfma_f32_32x32x16_bf16(v1, F1, oac1, 0, 0, 0); \
            v0 = *(const bf16x8*)&(PV)[lofs[2]];                                \
            v1 = *(const bf16x8*)&(PV)[lofs[2] + 2048];                         \
            oac0 = __builtin_amdgcn_mfma_f32_32x32x16_bf16(v0, F2, oac0, 0, 0, 0); \
            oac1 = __builtin_amdgcn_mfma_f32_32x32x16_bf16(v1, F2, oac1, 0, 0, 0); \
            v0 = *(const bf16x8*)&(PV)[lofs[3]];                                \
            v1 = *(const bf16x8*)&(PV)[lofs[3] + 2048];                         \
            oac0 = __builtin_amdgcn_mfma_f32_32x32x16_bf16(v0, F3, oac0, 0, 0, 0); \
            oac1 = __builtin_amdgcn_mfma_f32_32x32x16_bf16(v1, F3, oac1, 0, 0, 0); \
        }                                                                       \
        __builtin_amdgcn_s_setprio(0);                                          \
    } while (0)

    A_STAGE(0, KBUF(0), VBUF(0));
    if (nT > 1) A_STAGE(1, KBUF(1), VBUF(1));
    if (nT > 2) A_STAGE(2, KBUF(2), VBUF(2));

    for (int t = 0; t < nT; ++t) {
        const int rem = nT - 1 - t;          // tiles staged beyond t
        if (rem >= 2) { VMCNT(8); }
        else if (rem == 1) { VMCNT(4); }
        else { VMCNT(0); }
        __builtin_amdgcn_s_barrier();
        if (t + 3 < nT) A_STAGE(t + 3, KBUF((t + 3) & 3), VBUF((t + 3) & 3));

        short* curK = KBUF(t & 3);
        short* curV = VBUF(t & 3);
        if (t < nFull) TILE_BODY(false, curK, curV);
        else TILE_BODY(true, curK, curV);
    }
#undef TILE_BODY
#undef A_STAGE
#undef MK_FRAG
#undef KBUF
#undef VBUF

    // denominator: own-q partial + partner half
    float lt = l_run + __shfl_xor(l_run, 32);
    float rl2 = 1.f / lt;

    short* orow = O + rowbase + (size_t)q * DMODEL;
#pragma unroll
    for (int r2 = 0; r2 < 4; ++r2) {
        short4v pk0, pk1;
#pragma unroll
        for (int j = 0; j < 4; ++j) {
            pk0[j] = f2b(oac0[r2 * 4 + j] * rl2);
            pk1[j] = f2b(oac1[r2 * 4 + j] * rl2);
        }
        int d0 = r2 * 8 + 4 * g;
        *(short4v*)&orow[d0] = pk0;
        *(short4v*)&orow[32 + d0] = pk1;
    }
}

extern "C" void kernel_launch(void* const* d_in, const int* in_sizes, int n_in,
                              void* d_out, int out_size, void* d_ws, size_t ws_size,
                              hipStream_t stream) {
    const float* X = (const float*)d_in[0];
    const int* vlens = (const int*)d_in[1];
    const float* Wq = (const float*)d_in[2];
    const float* Wk = (const float*)d_in[3];
    const float* Wv = (const float*)d_in[4];
    const float* Wo = (const float*)d_in[5];
    float* out = (float*)d_out;

    short* Xb = (short*)d_ws;
    short* Wqb = Xb + (size_t)MROWS * DMODEL;
    short* Wkb = Wqb + (size_t)DMODEL * DMODEL;
    short* Wvb = Wkb + (size_t)DMODEL * DMODEL;
    short* Wob = Wvb + (size_t)DMODEL * DMODEL;
    short* Qb = Wob + (size_t)DMODEL * DMODEL;
    short* Kb = Qb + (size_t)MROWS * DMODEL;
    short* Vtb = Kb + (size_t)MROWS * DMODEL;  // Vt[b][h][d][key]
    short* Ob = Vtb + (size_t)MROWS * DMODEL;

    cvt_kernel<<<dim3(512, 5), 256, 0, stream>>>(X, Wq, Wk, Wv, Wo, Xb, Wqb, Wkb,
                                                 Wvb, Wob);
    gemm_bt<0><<<dim3(8, 32, 3), 256, 0, stream>>>(Xb, Wqb, Wkb, Wvb, Qb, Kb, Vtb,
                                                   nullptr, vlens, MROWS, DMODEL,
                                                   DMODEL);
    attn_kernel<<<dim3(512), 256, 0, stream>>>(Qb, Kb, Vtb, Ob, vlens);
    gemm_bt<1><<<dim3(8, 32, 1), 256, 0, stream>>>(Ob, Wob, Wob, Wob, nullptr,
                                                   nullptr, nullptr, out, nullptr,
                                                   MROWS, DMODEL, DMODEL);
}

// Round 18
// 101.777 us; speedup vs baseline: 1.0544x; 1.0043x over previous
//
#include <hip/hip_runtime.h>
#include <stdint.h>

#define S_LEN 2048
#define BATCH 2
#define DMODEL 1024
#define NHEAD 16
#define DK 64
#define MROWS (BATCH * S_LEN) /* 4096 */

typedef __attribute__((ext_vector_type(8))) short bf16x8;
typedef __attribute__((ext_vector_type(4))) float f32x4;
typedef __attribute__((ext_vector_type(16))) float f32x16;
typedef __attribute__((ext_vector_type(4))) short short4v;

#define VMCNT(N) asm volatile("s_waitcnt vmcnt(" #N ")" ::: "memory")

__device__ __forceinline__ short f2b(float f) {
    union { float f; uint32_t u; } c; c.f = f;
    uint32_t u = c.u;
    return (short)((u + 0x7fffu + ((u >> 16) & 1u)) >> 16);
}

__device__ __forceinline__ void gload16(const void* g, void* l) {
    __builtin_amdgcn_global_load_lds(
        (const __attribute__((address_space(1))) void*)g,
        (__attribute__((address_space(3))) void*)l, 16, 0, 0);
}

// ---------------------------------------------------------------- fp32 -> bf16
__global__ void cvt_kernel(const float* __restrict__ X, const float* __restrict__ Wq,
                           const float* __restrict__ Wk, const float* __restrict__ Wv,
                           const float* __restrict__ Wo,
                           short* __restrict__ Xb, short* __restrict__ Wqb,
                           short* __restrict__ Wkb, short* __restrict__ Wvb,
                           short* __restrict__ Wob) {
    const float* src; short* dst; int n4;
    switch (blockIdx.y) {
        case 0:  src = X;  dst = Xb;  n4 = MROWS * DMODEL / 4;  break;
        case 1:  src = Wq; dst = Wqb; n4 = DMODEL * DMODEL / 4; break;
        case 2:  src = Wk; dst = Wkb; n4 = DMODEL * DMODEL / 4; break;
        case 3:  src = Wv; dst = Wvb; n4 = DMODEL * DMODEL / 4; break;
        default: src = Wo; dst = Wob; n4 = DMODEL * DMODEL / 4; break;
    }
    for (int i = blockIdx.x * blockDim.x + threadIdx.x; i < n4;
         i += gridDim.x * blockDim.x) {
        float4 v = ((const float4*)src)[i];
        short4v o;
        o[0] = f2b(v.x); o[1] = f2b(v.y); o[2] = f2b(v.z); o[3] = f2b(v.w);
        ((short4v*)dst)[i] = o;
    }
}

// ------------------------------------------------- C = A * Bt^T  (bf16 MFMA)
// 3-deep LDS pipeline, counted vmcnt + raw s_barrier; mask-skip for K/V blocks
// beyond ceil64(vl) (R17-verified).
template <int OUT_F32>
__global__ __launch_bounds__(256) void gemm_bt(
    const short* __restrict__ A,
    const short* __restrict__ Bt0, const short* __restrict__ Bt1,
    const short* __restrict__ Bt2,
    short* __restrict__ Cb0, short* __restrict__ Cb1, short* __restrict__ Cb2,
    float* __restrict__ Cf, const int* __restrict__ vlens, int M, int N, int K) {
    __shared__ short sA[3][128 * 32];
    __shared__ short sB[3][128 * 32];

    const short* Bt = Bt0;
    short* Cb = Cb0;
    if (blockIdx.z == 1) { Bt = Bt1; Cb = Cb1; }
    else if (blockIdx.z == 2) { Bt = Bt2; Cb = Cb2; }

    const int brow = blockIdx.y * 128;
    if (!OUT_F32 && blockIdx.z >= 1 && vlens) {
        int vlb = vlens[brow >> 11];
        if (vlb <= 0 || vlb > S_LEN) vlb = S_LEN;
        else vlb = (vlb + 63) & ~63;
        if ((brow & (S_LEN - 1)) >= vlb) return;
    }

    const int tid = threadIdx.x;
    const int lane = tid & 63;
    const int wid = tid >> 6;
    const int wr = wid >> 1, wc = wid & 1;
    const int bcol = blockIdx.x * 128;
    const int lr = lane & 15;
    const int kh = (lane >> 4) << 3;
    const int swg = ((lr >> 1) & 3) << 3;
    const int khs = kh ^ swg;

    f32x4 acc[4][4] = {};

    const int idx0 = tid, idx1 = tid + 256;
    const int ar0 = idx0 >> 2, ak0 = ((idx0 & 3) << 3) ^ (((ar0 >> 1) & 3) << 3);
    const int ar1 = idx1 >> 2, ak1 = ((idx1 & 3) << 3) ^ (((ar1 >> 1) & 3) << 3);

    const short* gA0 = A + (size_t)(brow + ar0) * K + ak0;
    const short* gA1 = A + (size_t)(brow + ar1) * K + ak1;
    const short* gB0 = Bt + (size_t)(bcol + ar0) * K + ak0;
    const short* gB1 = Bt + (size_t)(bcol + ar1) * K + ak1;

#define G_STAGE(KT, PA, PB)                                   \
    do {                                                      \
        const int k0_ = (KT) << 5;                            \
        gload16(gA0 + k0_, (PA) + idx0 * 8);                  \
        gload16(gA1 + k0_, (PA) + idx1 * 8);                  \
        gload16(gB0 + k0_, (PB) + idx0 * 8);                  \
        gload16(gB1 + k0_, (PB) + idx1 * 8);                  \
    } while (0)

    const int nk = K >> 5;
    short* pA0 = &sA[0][0]; short* pA1 = &sA[1][0]; short* pA2 = &sA[2][0];
    short* pB0 = &sB[0][0]; short* pB1 = &sB[1][0]; short* pB2 = &sB[2][0];

    G_STAGE(0, pA0, pB0);
    G_STAGE(1, pA1, pB1);

    for (int kt = 0; kt < nk; ++kt) {
        if (kt == nk - 1) { VMCNT(0); } else { VMCNT(4); }
        __builtin_amdgcn_s_barrier();
        if (kt + 2 < nk) G_STAGE(kt + 2, pA2, pB2);

        bf16x8 a[4], b[4];
#pragma unroll
        for (int mt = 0; mt < 4; ++mt)
            a[mt] = *(const bf16x8*)&pA0[(wr * 64 + mt * 16 + lr) * 32 + khs];
#pragma unroll
        for (int nt = 0; nt < 4; ++nt)
            b[nt] = *(const bf16x8*)&pB0[(wc * 64 + nt * 16 + lr) * 32 + khs];
        __builtin_amdgcn_s_setprio(1);
#pragma unroll
        for (int mt = 0; mt < 4; ++mt)
#pragma unroll
            for (int nt = 0; nt < 4; ++nt)
                acc[mt][nt] = __builtin_amdgcn_mfma_f32_16x16x32_bf16(
                    a[mt], b[nt], acc[mt][nt], 0, 0, 0);
        __builtin_amdgcn_s_setprio(0);

        short* tA = pA0; pA0 = pA1; pA1 = pA2; pA2 = tA;
        short* tB = pB0; pB0 = pB1; pB1 = pB2; pB2 = tB;
    }
#undef G_STAGE

    const int rbase = (lane >> 4) << 2;
    const bool vtrans = (!OUT_F32) && (blockIdx.z == 2);
#pragma unroll
    for (int mt = 0; mt < 4; ++mt) {
#pragma unroll
        for (int nt = 0; nt < 4; ++nt) {
            if (vtrans) {
                int row0 = brow + wr * 64 + mt * 16 + rbase;
                int col = bcol + wc * 64 + nt * 16 + lr;
                int bb = row0 >> 11, key = row0 & 2047;
                int hh = col >> 6, d = col & 63;
                short4v pk;
#pragma unroll
                for (int j = 0; j < 4; ++j) pk[j] = f2b(acc[mt][nt][j]);
                *(short4v*)&Cb[((size_t)((bb * 16 + hh) * 64 + d)) * S_LEN + key] = pk;
            } else {
#pragma unroll
                for (int j = 0; j < 4; ++j) {
                    int row = brow + wr * 64 + mt * 16 + rbase + j;
                    int col = bcol + wc * 64 + nt * 16 + lr;
                    if (OUT_F32)
                        Cf[(size_t)row * N + col] = acc[mt][nt][j];
                    else
                        Cb[(size_t)row * N + col] = f2b(acc[mt][nt][j]);
                }
            }
        }
    }
}

// ------------------------------------------------------------- flash attention
// 32x32x16 MFMA, P in-register. T15 deferred-PV pipeline: per iter the MFMA
// cluster is QK(t) + PV(t-1) (inputs all ready), then softmax(t) builds the
// P fragments consumed next iter. Online-softmax order preserved (PV(t-1)
// lands before SM(t)'s rescale). 5-deep LDS (80KB = exactly 2 blocks/CU),
// stage t+3 ahead, VMCNT(8/4/0). Conflict-free swizzle (R17: conflicts=0).
__global__ __launch_bounds__(256, 2) void attn_kernel(
    const short* __restrict__ Q, const short* __restrict__ K,
    const short* __restrict__ Vt, short* __restrict__ O,
    const int* __restrict__ vlens) {
    __shared__ short sK[5][64 * 64];
    __shared__ short sV[5][64 * 64];

    const int tid = threadIdx.x;
    const int lane = tid & 63;
    const int w = tid >> 6;
    const int id = blockIdx.x;
    const int xcd = id & 7;
    const int r = id >> 3;
    const int b = (r >> 5) & 1;
    const int h = (xcd << 1) | (r & 1);
    const int qb = (r >> 1) & 15;          // 16 q-tiles of 128 rows
    const int rl_ = lane & 31;
    const int g = lane >> 5;

    int vl = vlens[b];
    if (vl < 0) vl = 0;
    if (vl > S_LEN) vl = S_LEN;
    const bool allm = (vl == 0);
    if (allm) vl = S_LEN;
    const int nT = (vl + 63) >> 6;
    const int nFull = ((vl & 63) == 0) ? nT : nT - 1;

    const size_t rowbase = (size_t)(b * S_LEN) * DMODEL + h * DK;
    const short* vt = Vt + ((size_t)((b * 16 + h) * 64)) * S_LEN;

    const int q = qb * 128 + w * 32 + rl_;
    const short* qA = Q + rowbase + (size_t)q * DMODEL;
    bf16x8 qf[4];
#pragma unroll
    for (int f = 0; f < 4; ++f)
        qf[f] = *(const bf16x8*)(qA + f * 16 + g * 8);
    if (allm) {
#pragma unroll
        for (int f = 0; f < 4; ++f)
#pragma unroll
            for (int i = 0; i < 8; ++i) qf[f][i] = 0;
    }

    f32x16 oac0 = {}, oac1 = {};
    float m_run = -1e30f, mc = -1e30f, l_run = 0.f;
    const float CEXP = 0.18033688011112042f;   // 0.125 * log2(e)
    const float THRADD = 44.361419556f;        // 8 / CEXP

    const int rsw = (((rl_ & 7) ^ ((rl_ >> 3) & 3)) << 3);
    int lofs[4];
#pragma unroll
    for (int f = 0; f < 4; ++f)
        lofs[f] = rl_ * 64 + ((f * 16 + g * 8) ^ rsw);

    const int kr = tid >> 3;
    const int kc = (((tid & 7) ^ (kr & 7) ^ ((kr >> 3) & 3)) << 3);
    const short* kBase = K + rowbase + (size_t)kr * DMODEL + kc;
    const short* vBase = vt + (size_t)kr * S_LEN + kc;

    short* const sK0 = &sK[0][0];
    short* const sV0 = &sV[0][0];
#define KBUF(i) (sK0 + (i) * 4096)
#define VBUF(i) (sV0 + (i) * 4096)

#define A_STAGE(T, PK, PV)                                                      \
    do {                                                                        \
        const short* kg_ = kBase + (size_t)((T) * 64) * DMODEL;                 \
        gload16(kg_, (PK) + tid * 8);                                           \
        gload16(kg_ + (size_t)32 * DMODEL, (PK) + (tid + 256) * 8);             \
        const short* vg_ = vBase + (T) * 64;                                    \
        gload16(vg_, (PV) + tid * 8);                                           \
        gload16(vg_ + (size_t)32 * S_LEN, (PV) + (tid + 256) * 8);              \
    } while (0)

#define MK_FRAG(A0, A1, A2, A3)                                                 \
    ({ union { uint32_t u[4]; bf16x8 v; } _f;                                   \
       _f.u[0] = (A0); _f.u[1] = (A1); _f.u[2] = (A2); _f.u[3] = (A3); _f.v; })

    bf16x8 pF0 = {}, pF1 = {}, pF2 = {}, pF3 = {};   // P fragments of tile t-1

#define PV_BODY(PV)                                                             \
    do {                                                                        \
        bf16x8 v0 = *(const bf16x8*)&(PV)[lofs[0]];                             \
        bf16x8 v1 = *(const bf16x8*)&(PV)[lofs[0] + 2048];                      \
        oac0 = __builtin_amdgcn_mfma_f32_32x32x16_bf16(v0, pF0, oac0, 0, 0, 0); \
        oac1 = __builtin_amdgcn_mfma_f32_32x32x16_bf16(v1, pF0, oac1, 0, 0, 0); \
        v0 = *(const bf16x8*)&(PV)[lofs[1]];                                    \
        v1 = *(const bf16x8*)&(PV)[lofs[1] + 2048];                             \
        oac0 = __builtin_amdgcn_mfma_f32_32x32x16_bf16(v0, pF1, oac0, 0, 0, 0); \
        oac1 = __builtin_amdgcn_mfma_f32_32x32x16_bf16(v1, pF1, oac1, 0, 0, 0); \
        v0 = *(const bf16x8*)&(PV)[lofs[2]];                                    \
        v1 = *(const bf16x8*)&(PV)[lofs[2] + 2048];                             \
        oac0 = __builtin_amdgcn_mfma_f32_32x32x16_bf16(v0, pF2, oac0, 0, 0, 0); \
        oac1 = __builtin_amdgcn_mfma_f32_32x32x16_bf16(v1, pF2, oac1, 0, 0, 0); \
        v0 = *(const bf16x8*)&(PV)[lofs[3]];                                    \
        v1 = *(const bf16x8*)&(PV)[lofs[3] + 2048];                             \
        oac0 = __builtin_amdgcn_mfma_f32_32x32x16_bf16(v0, pF3, oac0, 0, 0, 0); \
        oac1 = __builtin_amdgcn_mfma_f32_32x32x16_bf16(v1, pF3, oac1, 0, 0, 0); \
    } while (0)

#define SM_BODY(MASKED_C)                                                       \
    do {                                                                        \
        constexpr bool MASKED = MASKED_C;                                       \
        if (MASKED) {                                                           \
            _Pragma("unroll")                                                   \
            for (int rg = 0; rg < 16; ++rg) {                                   \
                int key0 = t * 64 + (rg & 3) + 8 * (rg >> 2) + 4 * g;           \
                if (key0 >= vl) s0[rg] = -3.0e38f;                              \
                if (key0 + 32 >= vl) s1[rg] = -3.0e38f;                         \
            }                                                                   \
        }                                                                       \
        float x0 = fmaxf(fmaxf(s0[0], s0[1]), fmaxf(s0[2], s0[3]));             \
        float x1 = fmaxf(fmaxf(s0[4], s0[5]), fmaxf(s0[6], s0[7]));             \
        float x2 = fmaxf(fmaxf(s0[8], s0[9]), fmaxf(s0[10], s0[11]));           \
        float x3 = fmaxf(fmaxf(s0[12], s0[13]), fmaxf(s0[14], s0[15]));         \
        float x4 = fmaxf(fmaxf(s1[0], s1[1]), fmaxf(s1[2], s1[3]));             \
        float x5 = fmaxf(fmaxf(s1[4], s1[5]), fmaxf(s1[6], s1[7]));             \
        float x6 = fmaxf(fmaxf(s1[8], s1[9]), fmaxf(s1[10], s1[11]));           \
        float x7 = fmaxf(fmaxf(s1[12], s1[13]), fmaxf(s1[14], s1[15]));         \
        float px = fmaxf(fmaxf(fmaxf(x0, x1), fmaxf(x2, x3)),                   \
                         fmaxf(fmaxf(x4, x5), fmaxf(x6, x7)));                  \
        if (__any(px > m_run + THRADD)) {                                       \
            float mx = fmaxf(px, __shfl_xor(px, 32));                           \
            mx = fmaxf(mx, m_run);                                              \
            float scl = __builtin_exp2f((m_run - mx) * CEXP);                   \
            m_run = mx; mc = mx * CEXP;                                         \
            l_run *= scl;                                                       \
            _Pragma("unroll")                                                   \
            for (int i = 0; i < 16; ++i) { oac0[i] *= scl; oac1[i] *= scl; }    \
        }                                                                       \
        uint32_t P0[8], P1[8];                                                  \
        float ls = 0.f;                                                         \
        _Pragma("unroll")                                                       \
        for (int i = 0; i < 8; ++i) {                                           \
            float a0 = __builtin_exp2f(__builtin_fmaf(s0[2 * i], CEXP, -mc));   \
            float a1 = __builtin_exp2f(__builtin_fmaf(s0[2 * i + 1], CEXP, -mc)); \
            float b0 = __builtin_exp2f(__builtin_fmaf(s1[2 * i], CEXP, -mc));   \
            float b1 = __builtin_exp2f(__builtin_fmaf(s1[2 * i + 1], CEXP, -mc)); \
            ls += (a0 + a1) + (b0 + b1);                                        \
            asm("v_cvt_pk_bf16_f32 %0, %1, %2" : "=v"(P0[i]) : "v"(a0), "v"(a1)); \
            asm("v_cvt_pk_bf16_f32 %0, %1, %2" : "=v"(P1[i]) : "v"(b0), "v"(b1)); \
        }                                                                       \
        l_run += ls;                                                            \
        asm volatile("v_permlane32_swap_b32 %0, %1" : "+v"(P0[0]), "+v"(P0[2])); \
        asm volatile("v_permlane32_swap_b32 %0, %1" : "+v"(P0[1]), "+v"(P0[3])); \
        asm volatile("v_permlane32_swap_b32 %0, %1" : "+v"(P0[4]), "+v"(P0[6])); \
        asm volatile("v_permlane32_swap_b32 %0, %1" : "+v"(P0[5]), "+v"(P0[7])); \
        asm volatile("v_permlane32_swap_b32 %0, %1" : "+v"(P1[0]), "+v"(P1[2])); \
        asm volatile("v_permlane32_swap_b32 %0, %1" : "+v"(P1[1]), "+v"(P1[3])); \
        asm volatile("v_permlane32_swap_b32 %0, %1" : "+v"(P1[4]), "+v"(P1[6])); \
        asm volatile("v_permlane32_swap_b32 %0, %1" : "+v"(P1[5]), "+v"(P1[7])); \
        pF0 = MK_FRAG(P0[0], P0[1], P0[2], P0[3]);                              \
        pF1 = MK_FRAG(P0[4], P0[5], P0[6], P0[7]);                              \
        pF2 = MK_FRAG(P1[0], P1[1], P1[2], P1[3]);                              \
        pF3 = MK_FRAG(P1[4], P1[5], P1[6], P1[7]);                              \
    } while (0)

    A_STAGE(0, KBUF(0), VBUF(0));
    if (nT > 1) A_STAGE(1, KBUF(1), VBUF(1));
    if (nT > 2) A_STAGE(2, KBUF(2), VBUF(2));

    int cur = 0, stg = 3, prv = 4;
    for (int t = 0; t < nT; ++t) {
        const int rem = nT - 1 - t;
        if (rem >= 2) { VMCNT(8); }
        else if (rem == 1) { VMCNT(4); }
        else { VMCNT(0); }
        __builtin_amdgcn_s_barrier();
        if (t + 3 < nT) A_STAGE(t + 3, KBUF(stg), VBUF(stg));

        const short* PK = KBUF(cur);
        f32x16 s0 = {}, s1 = {};
        __builtin_amdgcn_s_setprio(1);
#pragma unroll
        for (int f = 0; f < 4; ++f) {
            bf16x8 ka = *(const bf16x8*)&PK[lofs[f]];
            bf16x8 kb2 = *(const bf16x8*)&PK[lofs[f] + 2048];
            s0 = __builtin_amdgcn_mfma_f32_32x32x16_bf16(ka, qf[f], s0, 0, 0, 0);
            s1 = __builtin_amdgcn_mfma_f32_32x32x16_bf16(kb2, qf[f], s1, 0, 0, 0);
        }
        if (t > 0) PV_BODY(VBUF(prv));   // tile t-1: inputs all ready
        __builtin_amdgcn_s_setprio(0);

        if (t < nFull) SM_BODY(false);
        else SM_BODY(true);

        prv = cur;
        cur = (cur == 4) ? 0 : cur + 1;
        stg = (stg == 4) ? 0 : stg + 1;
    }
    // epilogue: PV of the last tile
    __builtin_amdgcn_s_setprio(1);
    PV_BODY(VBUF(prv));
    __builtin_amdgcn_s_setprio(0);

#undef SM_BODY
#undef PV_BODY
#undef A_STAGE
#undef MK_FRAG
#undef KBUF
#undef VBUF

    float lt = l_run + __shfl_xor(l_run, 32);
    float rl2 = 1.f / lt;

    short* orow = O + rowbase + (size_t)q * DMODEL;
#pragma unroll
    for (int r2 = 0; r2 < 4; ++r2) {
        short4v pk0, pk1;
#pragma unroll
        for (int j = 0; j < 4; ++j) {
            pk0[j] = f2b(oac0[r2 * 4 + j] * rl2);
            pk1[j] = f2b(oac1[r2 * 4 + j] * rl2);
        }
        int d0 = r2 * 8 + 4 * g;
        *(short4v*)&orow[d0] = pk0;
        *(short4v*)&orow[32 + d0] = pk1;
    }
}

extern "C" void kernel_launch(void* const* d_in, const int* in_sizes, int n_in,
                              void* d_out, int out_size, void* d_ws, size_t ws_size,
                              hipStream_t stream) {
    const float* X = (const float*)d_in[0];
    const int* vlens = (const int*)d_in[1];
    const float* Wq = (const float*)d_in[2];
    const float* Wk = (const float*)d_in[3];
    const float* Wv = (const float*)d_in[4];
    const float* Wo = (const float*)d_in[5];
    float* out = (float*)d_out;

    short* Xb = (short*)d_ws;
    short* Wqb = Xb + (size_t)MROWS * DMODEL;
    short* Wkb = Wqb + (size_t)DMODEL * DMODEL;
    short* Wvb = Wkb + (size_t)DMODEL * DMODEL;
    short* Wob = Wvb + (size_t)DMODEL * DMODEL;
    short* Qb = Wob + (size_t)DMODEL * DMODEL;
    short* Kb = Qb + (size_t)MROWS * DMODEL;
    short* Vtb = Kb + (size_t)MROWS * DMODEL;  // Vt[b][h][d][key]
    short* Ob = Vtb + (size_t)MROWS * DMODEL;

    cvt_kernel<<<dim3(512, 5), 256, 0, stream>>>(X, Wq, Wk, Wv, Wo, Xb, Wqb, Wkb,
                                                 Wvb, Wob);
    gemm_bt<0><<<dim3(8, 32, 3), 256, 0, stream>>>(Xb, Wqb, Wkb, Wvb, Qb, Kb, Vtb,
                                                   nullptr, vlens, MROWS, DMODEL,
                                                   DMODEL);
    attn_kernel<<<dim3(512), 256, 0, stream>>>(Qb, Kb, Vtb, Ob, vlens);
    gemm_bt<1><<<dim3(8, 32, 1), 256, 0, stream>>>(Ob, Wob, Wob, Wob, nullptr,
                                                   nullptr, nullptr, out, nullptr,
                                                   MROWS, DMODEL, DMODEL);
}